// Round 1
// baseline (18.269 us; speedup 1.0000x reference)
//
#include <hip/hip_runtime.h>
#include <math.h>

constexpr int Bn = 1024, Tn = 6, Vn = 100, Pn = 20, Cn = 3;

__global__ __launch_bounds__(128) void pmbl_main(
    const float* __restrict__ ego,      // (B, T, 2)
    const float* __restrict__ lane,     // (B, V, P, 2)
    const float* __restrict__ score,    // (B, V, C)
    float* __restrict__ bsum)           // (B) per-b loss sums
{
    const int b = blockIdx.x;
    const int tid = threadIdx.x;

    __shared__ unsigned long long red[2][Tn];
    __shared__ int interMask;

    // cumsum: pred (px,py) and starts (sx,sy) -- computed redundantly per thread
    float px[Tn], py[Tn], sx[Tn], sy[Tn];
    {
        const float* e = ego + (size_t)b * (Tn * 2);
        float cx = 0.f, cy = 0.f;
        #pragma unroll
        for (int t = 0; t < Tn; ++t) {
            sx[t] = cx; sy[t] = cy;
            cx += e[2 * t];
            cy += e[2 * t + 1];
            px[t] = cx; py[t] = cy;
        }
    }

    // phase 1: per-lane min over P of SQUARED distance, for each t
    float dmin[Tn];
    #pragma unroll
    for (int t = 0; t < Tn; ++t) dmin[t] = __builtin_inff();

    if (tid < Vn) {
        const float sc = score[(size_t)b * (Vn * Cn) + tid * Cn + 2];
        const bool nb = sc < 0.5f;  // not a bound -> masked to 1e6
        const float4* lp4 = reinterpret_cast<const float4*>(
            lane + ((size_t)b * Vn + tid) * (Pn * 2));
        #pragma unroll
        for (int pp = 0; pp < Pn / 2; ++pp) {
            float4 q = lp4[pp];
            float x0 = nb ? 1e6f : fmaf(q.x, 30.f, -15.f);
            float y0 = nb ? 1e6f : fmaf(q.y, 60.f, -30.f);
            float x1 = nb ? 1e6f : fmaf(q.z, 30.f, -15.f);
            float y1 = nb ? 1e6f : fmaf(q.w, 60.f, -30.f);
            #pragma unroll
            for (int t = 0; t < Tn; ++t) {
                float dx0 = px[t] - x0, dy0 = py[t] - y0;
                float s0 = dx0 * dx0 + dy0 * dy0;
                float dx1 = px[t] - x1, dy1 = py[t] - y1;
                float s1 = dx1 * dx1 + dy1 * dy1;
                dmin[t] = fminf(dmin[t], fminf(s0, s1));
            }
        }
    }

    // pack (sq_bits << 32) | v : u64 min == (min value, first-occurrence argmin)
    unsigned long long pk[Tn];
    #pragma unroll
    for (int t = 0; t < Tn; ++t)
        pk[t] = (((unsigned long long)__float_as_uint(dmin[t])) << 32) | (unsigned)tid;

    // butterfly reduce within each 64-lane wave
    #pragma unroll
    for (int off = 32; off > 0; off >>= 1) {
        #pragma unroll
        for (int t = 0; t < Tn; ++t) {
            unsigned long long o = __shfl_xor(pk[t], off);
            pk[t] = (o < pk[t]) ? o : pk[t];
        }
    }

    if (tid == 0) interMask = 0;
    if ((tid & 63) == 0) {
        #pragma unroll
        for (int t = 0; t < Tn; ++t) red[tid >> 6][t] = pk[t];
    }
    __syncthreads();

    unsigned long long comb[Tn];
    #pragma unroll
    for (int t = 0; t < Tn; ++t) {
        unsigned long long a = red[0][t], c = red[1][t];
        comb[t] = (c < a) ? c : a;
    }

    // phase 2: 6*19 = 114 segment-intersection tests, one per thread
    if (tid < Tn * (Pn - 1)) {
        const int t = tid / (Pn - 1);
        const int s = tid % (Pn - 1);
        const int vt = (int)(comb[t] & 0xffffffffu);
        const float scv = score[(size_t)b * (Vn * Cn) + vt * Cn + 2];
        const bool nb = scv < 0.5f;
        const float* lp = lane + ((size_t)b * Vn + vt) * (Pn * 2);
        float ax = nb ? 1e6f : fmaf(lp[2 * s + 0], 30.f, -15.f);
        float ay = nb ? 1e6f : fmaf(lp[2 * s + 1], 60.f, -30.f);
        float bx = nb ? 1e6f : fmaf(lp[2 * s + 2], 30.f, -15.f);
        float by = nb ? 1e6f : fmaf(lp[2 * s + 3], 60.f, -30.f);
        float d1x = px[t] - sx[t], d1y = py[t] - sy[t];
        float d2x = bx - ax, d2y = by - ay;
        float det = d1x * d2y - d1y * d2x;
        if (det != 0.f) {
            float dx = ax - sx[t], dy = ay - sy[t];
            float tt = (dx * d2y - dy * d2x) / det;
            float uu = (dx * d1y - dy * d1x) / det;
            if (tt >= 0.f && tt <= 1.f && uu >= 0.f && uu <= 1.f)
                atomicOr(&interMask, 1 << t);
        }
    }
    __syncthreads();

    if (tid == 0) {
        const int im = interMask;
        int first_t = Tn;
        #pragma unroll
        for (int t = Tn - 1; t >= 0; --t)
            if ((im >> t) & 1) first_t = t;
        float sum = 0.f;
        for (int t = 0; t < first_t; ++t) {
            float d = sqrtf(__uint_as_float((unsigned)(comb[t] >> 32)));
            sum += (d > 1.f) ? 0.f : (1.f - d);
        }
        bsum[b] = sum;
    }
}

__global__ __launch_bounds__(256) void pmbl_reduce(
    const float* __restrict__ bsum, float* __restrict__ out)
{
    __shared__ double sm[4];
    const int tid = threadIdx.x;
    double s = 0.0;
    for (int i = tid; i < Bn; i += 256) s += (double)bsum[i];
    #pragma unroll
    for (int off = 32; off > 0; off >>= 1) s += __shfl_xor(s, off);
    if ((tid & 63) == 0) sm[tid >> 6] = s;
    __syncthreads();
    if (tid == 0) {
        double tot = sm[0] + sm[1] + sm[2] + sm[3];
        out[0] = (float)(tot / (double)(Bn * Tn));
    }
}

extern "C" void kernel_launch(void* const* d_in, const int* in_sizes, int n_in,
                              void* d_out, int out_size, void* d_ws, size_t ws_size,
                              hipStream_t stream) {
    const float* ego   = (const float*)d_in[0];
    const float* lane  = (const float*)d_in[1];
    const float* score = (const float*)d_in[2];
    float* out  = (float*)d_out;
    float* bsum = (float*)d_ws;

    pmbl_main<<<Bn, 128, 0, stream>>>(ego, lane, score, bsum);
    pmbl_reduce<<<1, 256, 0, stream>>>(bsum, out);
}